// Round 1
// baseline (3338.160 us; speedup 1.0000x reference)
//
#include <hip/hip_runtime.h>
#include <math.h>

#define N_NODES 50000
#define N_EDGES 800000
#define DIM 256
#define HEADS 8
#define DIM_OUT 32
#define INNER 256  // HEADS*DIM_OUT

// ---------------------------------------------------------------------------
// fp32 GEMM with bias: C[M,256] = A[M,256] @ W[256,256] + bias
// 64x64 tile, BK=16, 256 threads, 4x4 microtile.
// ---------------------------------------------------------------------------
__global__ __launch_bounds__(256) void gemm_bias(
    const float* __restrict__ A,    // [M,256]
    const float* __restrict__ W,    // [256,256]
    const float* __restrict__ bias, // [256]
    float* __restrict__ C)          // [M,256]
{
    const int M = N_NODES;
    const int bm = blockIdx.x;
    const int bn = blockIdx.y;
    const int t  = threadIdx.x;

    // +4 pad keeps float4 alignment (68 % 4 == 0) and gives 2-way-max bank
    // aliasing on stores (free per m136).
    __shared__ __align__(16) float As[16][68]; // [k][m]
    __shared__ __align__(16) float Bs[16][68]; // [k][n]

    const int tm = (t & 15) * 4;  // row within tile
    const int tn = (t >> 4) * 4;  // col within tile
    const int row0 = bm * 64;
    const int col0 = bn * 64;

    float acc[4][4] = {};

    for (int k0 = 0; k0 < 256; k0 += 16) {
        // A tile: 64 rows x 16 k
        #pragma unroll
        for (int i = 0; i < 4; i++) {
            int m_l = (t >> 4) + i * 16;
            int k_l = t & 15;
            int r = row0 + m_l;
            As[k_l][m_l] = (r < M) ? A[(size_t)r * 256 + k0 + k_l] : 0.0f;
        }
        // B tile: 16 k x 64 n (fully coalesced)
        #pragma unroll
        for (int i = 0; i < 4; i++) {
            int k_l = (t >> 6) + i * 4;
            int n_l = t & 63;
            Bs[k_l][n_l] = W[(size_t)(k0 + k_l) * 256 + col0 + n_l];
        }
        __syncthreads();
        #pragma unroll
        for (int kk = 0; kk < 16; kk++) {
            float4 a = *(const float4*)&As[kk][tm];
            float4 b = *(const float4*)&Bs[kk][tn];
            float av[4] = {a.x, a.y, a.z, a.w};
            float bv[4] = {b.x, b.y, b.z, b.w};
            #pragma unroll
            for (int i2 = 0; i2 < 4; i2++)
                #pragma unroll
                for (int j2 = 0; j2 < 4; j2++)
                    acc[i2][j2] += av[i2] * bv[j2];
        }
        __syncthreads();
    }

    #pragma unroll
    for (int i2 = 0; i2 < 4; i2++) {
        int r = row0 + tm + i2;
        if (r < M) {
            float4 o;
            o.x = acc[i2][0] + bias[col0 + tn + 0];
            o.y = acc[i2][1] + bias[col0 + tn + 1];
            o.z = acc[i2][2] + bias[col0 + tn + 2];
            o.w = acc[i2][3] + bias[col0 + tn + 3];
            *(float4*)&C[(size_t)r * 256 + col0 + tn] = o;
        }
    }
}

// ---------------------------------------------------------------------------
// Kernel 2: per-edge scores (8 heads) + segment-max via uint-encoded atomicMax
// One wave per edge; lane l holds elements [4l,4l+4); head = l>>3.
// ---------------------------------------------------------------------------
__device__ __forceinline__ unsigned enc_f32(float f) {
    unsigned u = __float_as_uint(f);
    return (u & 0x80000000u) ? ~u : (u | 0x80000000u);
}
__device__ __forceinline__ float dec_f32(unsigned u) {
    unsigned b = (u & 0x80000000u) ? (u ^ 0x80000000u) : ~u;
    return __uint_as_float(b);
}

__global__ __launch_bounds__(256) void edge_scores(
    const float* __restrict__ q, const float* __restrict__ k,
    const int* __restrict__ src, const int* __restrict__ dst,
    float* __restrict__ scores, unsigned* __restrict__ m_u)
{
    int edge = blockIdx.x * 4 + (threadIdx.x >> 6);
    int lane = threadIdx.x & 63;
    int s = src[edge], d = dst[edge];
    float4 qv = *(const float4*)(q + (size_t)s * 256 + lane * 4);
    float4 kv = *(const float4*)(k + (size_t)d * 256 + lane * 4);
    float part = qv.x * kv.x + qv.y * kv.y + qv.z * kv.z + qv.w * kv.w;
    part += __shfl_xor(part, 1);
    part += __shfl_xor(part, 2);
    part += __shfl_xor(part, 4);
    if ((lane & 7) == 0) {
        int h = lane >> 3;
        float score = part * 0.17677669529663687f;  // 1/sqrt(32)
        scores[(size_t)edge * 8 + h] = score;
        atomicMax(m_u + (size_t)d * 8 + h, enc_f32(score));
    }
}

// ---------------------------------------------------------------------------
// Kernel 3: w = exp(score - m[dst]); z[dst] += w  (one thread per (e,h))
// ---------------------------------------------------------------------------
__global__ __launch_bounds__(256) void edge_exp(
    const int* __restrict__ dst,
    float* __restrict__ scores, const unsigned* __restrict__ m_u,
    float* __restrict__ z)
{
    int idx = blockIdx.x * 256 + threadIdx.x;  // < 6.4M
    int e = idx >> 3, h = idx & 7;
    int d = dst[e];
    float m = dec_f32(m_u[(size_t)d * 8 + h]);
    float w = __expf(scores[idx] - m);
    scores[idx] = w;
    unsafeAtomicAdd(z + (size_t)d * 8 + h, w);
}

// ---------------------------------------------------------------------------
// Kernel 4: out[dst] += p * v[src]; one wave per edge, 4 f32 atomics per lane
// ---------------------------------------------------------------------------
__global__ __launch_bounds__(256) void edge_aggregate(
    const float* __restrict__ v,
    const int* __restrict__ src, const int* __restrict__ dst,
    const float* __restrict__ scores, const float* __restrict__ z,
    float* __restrict__ out)
{
    int edge = blockIdx.x * 4 + (threadIdx.x >> 6);
    int lane = threadIdx.x & 63;
    int s = src[edge], d = dst[edge];
    int h = lane >> 3;
    float w = scores[(size_t)edge * 8 + h];
    float zz = z[(size_t)d * 8 + h];
    float p = w / fmaxf(zz, 1e-16f);
    float4 vv = *(const float4*)(v + (size_t)s * 256 + lane * 4);
    float* o = out + (size_t)d * 256 + lane * 4;
    unsafeAtomicAdd(o + 0, p * vv.x);
    unsafeAtomicAdd(o + 1, p * vv.y);
    unsafeAtomicAdd(o + 2, p * vv.z);
    unsafeAtomicAdd(o + 3, p * vv.w);
}

// ---------------------------------------------------------------------------
extern "C" void kernel_launch(void* const* d_in, const int* in_sizes, int n_in,
                              void* d_out, int out_size, void* d_ws, size_t ws_size,
                              hipStream_t stream) {
    const float* x  = (const float*)d_in[0];
    const float* Wq = (const float*)d_in[1];
    const float* bq = (const float*)d_in[2];
    const float* Wk = (const float*)d_in[3];
    const float* bk = (const float*)d_in[4];
    const float* Wv = (const float*)d_in[5];
    const float* bv = (const float*)d_in[6];
    const int* src  = (const int*)d_in[7];
    const int* dst  = (const int*)d_in[8];
    float* out = (float*)d_out;

    // workspace layout (fp32 unless noted): q,k,v [N,256] = 51.2MB each;
    // scores [E,8] = 25.6MB; m_u [N,8] u32 = 1.6MB; z [N,8] = 1.6MB. ~182MB.
    float* q      = (float*)d_ws;
    float* k      = q + (size_t)N_NODES * INNER;
    float* v      = k + (size_t)N_NODES * INNER;
    float* scores = v + (size_t)N_NODES * INNER;
    unsigned* m_u = (unsigned*)(scores + (size_t)N_EDGES * HEADS);
    float* z      = (float*)(m_u + (size_t)N_NODES * HEADS);

    // d_out / d_ws are poisoned 0xAA before every call — zero the accumulators.
    hipMemsetAsync(out, 0, (size_t)N_NODES * INNER * sizeof(float), stream);
    hipMemsetAsync(m_u, 0, (size_t)N_NODES * HEADS * sizeof(unsigned), stream);
    hipMemsetAsync(z,   0, (size_t)N_NODES * HEADS * sizeof(float), stream);

    dim3 gemm_grid((N_NODES + 63) / 64, 4);
    gemm_bias<<<gemm_grid, 256, 0, stream>>>(x, Wq, bq, q);
    gemm_bias<<<gemm_grid, 256, 0, stream>>>(x, Wk, bk, k);
    gemm_bias<<<gemm_grid, 256, 0, stream>>>(x, Wv, bv, v);

    edge_scores<<<N_EDGES / 4, 256, 0, stream>>>(q, k, src, dst, scores, m_u);
    edge_exp<<<(N_EDGES * HEADS) / 256, 256, 0, stream>>>(dst, scores, m_u, z);
    edge_aggregate<<<N_EDGES / 4, 256, 0, stream>>>(v, src, dst, scores, z, out);
}

// Round 2
// 978.469 us; speedup vs baseline: 3.4116x; 3.4116x over previous
//
#include <hip/hip_runtime.h>
#include <math.h>

#define N_NODES 50000
#define N_EDGES 800000
#define DIM 256
#define HEADS 8
#define DIM_OUT 32
#define INNER 256  // HEADS*DIM_OUT

// ---------------------------------------------------------------------------
// fp32 GEMM with bias: C[M,256] = A[M,256] @ W[256,256] + bias
// 64x64 tile, BK=16, 256 threads, 4x4 microtile.
// ---------------------------------------------------------------------------
__global__ __launch_bounds__(256) void gemm_bias(
    const float* __restrict__ A,    // [M,256]
    const float* __restrict__ W,    // [256,256]
    const float* __restrict__ bias, // [256]
    float* __restrict__ C)          // [M,256]
{
    const int M = N_NODES;
    const int bm = blockIdx.x;
    const int bn = blockIdx.y;
    const int t  = threadIdx.x;

    __shared__ __align__(16) float As[16][68]; // [k][m]
    __shared__ __align__(16) float Bs[16][68]; // [k][n]

    const int tm = (t & 15) * 4;  // row within tile
    const int tn = (t >> 4) * 4;  // col within tile
    const int row0 = bm * 64;
    const int col0 = bn * 64;

    float acc[4][4] = {};

    for (int k0 = 0; k0 < 256; k0 += 16) {
        #pragma unroll
        for (int i = 0; i < 4; i++) {
            int m_l = (t >> 4) + i * 16;
            int k_l = t & 15;
            int r = row0 + m_l;
            As[k_l][m_l] = (r < M) ? A[(size_t)r * 256 + k0 + k_l] : 0.0f;
        }
        #pragma unroll
        for (int i = 0; i < 4; i++) {
            int k_l = (t >> 6) + i * 4;
            int n_l = t & 63;
            Bs[k_l][n_l] = W[(size_t)(k0 + k_l) * 256 + col0 + n_l];
        }
        __syncthreads();
        #pragma unroll
        for (int kk = 0; kk < 16; kk++) {
            float4 a = *(const float4*)&As[kk][tm];
            float4 b = *(const float4*)&Bs[kk][tn];
            float av[4] = {a.x, a.y, a.z, a.w};
            float bv[4] = {b.x, b.y, b.z, b.w};
            #pragma unroll
            for (int i2 = 0; i2 < 4; i2++)
                #pragma unroll
                for (int j2 = 0; j2 < 4; j2++)
                    acc[i2][j2] += av[i2] * bv[j2];
        }
        __syncthreads();
    }

    #pragma unroll
    for (int i2 = 0; i2 < 4; i2++) {
        int r = row0 + tm + i2;
        if (r < M) {
            float4 o;
            o.x = acc[i2][0] + bias[col0 + tn + 0];
            o.y = acc[i2][1] + bias[col0 + tn + 1];
            o.z = acc[i2][2] + bias[col0 + tn + 2];
            o.w = acc[i2][3] + bias[col0 + tn + 3];
            *(float4*)&C[(size_t)r * 256 + col0 + tn] = o;
        }
    }
}

// ---------------------------------------------------------------------------
// Edge scores + segment-max via uint-encoded atomicMax. One wave per edge.
// ---------------------------------------------------------------------------
__device__ __forceinline__ unsigned enc_f32(float f) {
    unsigned u = __float_as_uint(f);
    return (u & 0x80000000u) ? ~u : (u | 0x80000000u);
}
__device__ __forceinline__ float dec_f32(unsigned u) {
    unsigned b = (u & 0x80000000u) ? (u ^ 0x80000000u) : ~u;
    return __uint_as_float(b);
}

__global__ __launch_bounds__(256) void edge_scores(
    const float* __restrict__ q, const float* __restrict__ k,
    const int* __restrict__ src, const int* __restrict__ dst,
    float* __restrict__ scores, unsigned* __restrict__ m_u)
{
    int edge = blockIdx.x * 4 + (threadIdx.x >> 6);
    int lane = threadIdx.x & 63;
    int s = src[edge], d = dst[edge];
    float4 qv = *(const float4*)(q + (size_t)s * 256 + lane * 4);
    float4 kv = *(const float4*)(k + (size_t)d * 256 + lane * 4);
    float part = qv.x * kv.x + qv.y * kv.y + qv.z * kv.z + qv.w * kv.w;
    part += __shfl_xor(part, 1);
    part += __shfl_xor(part, 2);
    part += __shfl_xor(part, 4);
    if ((lane & 7) == 0) {
        int h = lane >> 3;
        float score = part * 0.17677669529663687f;  // 1/sqrt(32)
        scores[(size_t)edge * 8 + h] = score;
        atomicMax(m_u + (size_t)d * 8 + h, enc_f32(score));
    }
}

// ---------------------------------------------------------------------------
// w = exp(score - m[dst]); z[dst] += w  (one thread per (e,h))
// ---------------------------------------------------------------------------
__global__ __launch_bounds__(256) void edge_exp(
    const int* __restrict__ dst,
    float* __restrict__ scores, const unsigned* __restrict__ m_u,
    float* __restrict__ z)
{
    int idx = blockIdx.x * 256 + threadIdx.x;  // < 6.4M
    int e = idx >> 3, h = idx & 7;
    int d = dst[e];
    float m = dec_f32(m_u[(size_t)d * 8 + h]);
    float w = __expf(scores[idx] - m);
    scores[idx] = w;
    unsafeAtomicAdd(z + (size_t)d * 8 + h, w);
}

// ---------------------------------------------------------------------------
// CSR build: histogram -> single-block scan -> scatter
// ---------------------------------------------------------------------------
__global__ __launch_bounds__(256) void deg_hist(
    const int* __restrict__ dst, int* __restrict__ deg)
{
    int e = blockIdx.x * 256 + threadIdx.x;
    if (e < N_EDGES) atomicAdd(deg + dst[e], 1);
}

// Single block, 256 threads. Each thread serially sums a contiguous chunk,
// block-scan of the 256 chunk sums, second pass writes prefix.
__global__ __launch_bounds__(256) void scan_deg(
    const int* __restrict__ deg, int* __restrict__ rowptr)
{
    const int CH = (N_NODES + 255) / 256;  // 196
    int t = threadIdx.x;
    int beg = t * CH;
    int end = min(beg + CH, N_NODES);
    int sum = 0;
    for (int i = beg; i < end; i++) sum += deg[i];

    __shared__ int s[256];
    s[t] = sum;
    __syncthreads();
    // Hillis-Steele inclusive scan
    for (int off = 1; off < 256; off <<= 1) {
        int u = (t >= off) ? s[t - off] : 0;
        __syncthreads();
        s[t] += u;
        __syncthreads();
    }
    int prefix = s[t] - sum;  // exclusive prefix of this chunk
    int run = prefix;
    for (int i = beg; i < end; i++) {
        run += deg[i];
        rowptr[i + 1] = run;   // inclusive cumsum -> rowptr[i+1]
    }
    if (t == 0) rowptr[0] = 0;
}

__global__ __launch_bounds__(256) void csr_scatter(
    const int* __restrict__ dst, const int* __restrict__ rowptr,
    int* __restrict__ fill, int* __restrict__ edge_list)
{
    int e = blockIdx.x * 256 + threadIdx.x;
    if (e >= N_EDGES) return;
    int d = dst[e];
    int pos = rowptr[d] + atomicAdd(fill + d, 1);
    edge_list[pos] = e;
}

// ---------------------------------------------------------------------------
// One wave per dst node: walk incoming edges, acc += p * v[src], single write.
// Lane l: head = l>>3, output dims [4l, 4l+4). No atomics.
// ---------------------------------------------------------------------------
__global__ __launch_bounds__(256) void node_aggregate(
    const float* __restrict__ v,
    const int* __restrict__ src,
    const float* __restrict__ scores,  // exp-weights after edge_exp
    const float* __restrict__ z,
    const int* __restrict__ rowptr, const int* __restrict__ edge_list,
    float* __restrict__ out)
{
    int node = blockIdx.x * 4 + (threadIdx.x >> 6);
    int lane = threadIdx.x & 63;
    if (node >= N_NODES) return;
    int beg = rowptr[node], end = rowptr[node + 1];
    int h = lane >> 3;
    float zz = z[(size_t)node * 8 + h];
    float inv = 1.0f / fmaxf(zz, 1e-16f);

    float ax = 0.f, ay = 0.f, az = 0.f, aw = 0.f;
    for (int i = beg; i < end; i++) {
        int e = edge_list[i];
        int s = src[e];
        float p = scores[(size_t)e * 8 + h] * inv;
        float4 vv = *(const float4*)(v + (size_t)s * 256 + lane * 4);
        ax += p * vv.x;
        ay += p * vv.y;
        az += p * vv.z;
        aw += p * vv.w;
    }
    float4 o = {ax, ay, az, aw};
    *(float4*)(out + (size_t)node * 256 + lane * 4) = o;
}

// ---------------------------------------------------------------------------
extern "C" void kernel_launch(void* const* d_in, const int* in_sizes, int n_in,
                              void* d_out, int out_size, void* d_ws, size_t ws_size,
                              hipStream_t stream) {
    const float* x  = (const float*)d_in[0];
    const float* Wq = (const float*)d_in[1];
    const float* bq = (const float*)d_in[2];
    const float* Wk = (const float*)d_in[3];
    const float* bk = (const float*)d_in[4];
    const float* Wv = (const float*)d_in[5];
    const float* bv = (const float*)d_in[6];
    const int* src  = (const int*)d_in[7];
    const int* dst  = (const int*)d_in[8];
    float* out = (float*)d_out;

    // workspace layout: q,k,v [N,256] f32; scores [E,8] f32; m_u [N,8] u32;
    // z [N,8] f32; deg [N] i32; rowptr [N+1] i32; fill [N] i32; edge_list [E] i32
    float* q      = (float*)d_ws;
    float* k      = q + (size_t)N_NODES * INNER;
    float* v      = k + (size_t)N_NODES * INNER;
    float* scores = v + (size_t)N_NODES * INNER;
    unsigned* m_u = (unsigned*)(scores + (size_t)N_EDGES * HEADS);
    float* z      = (float*)(m_u + (size_t)N_NODES * HEADS);
    int* deg      = (int*)(z + (size_t)N_NODES * HEADS);
    int* rowptr   = deg + N_NODES;
    int* fill     = rowptr + (N_NODES + 1);
    int* edge_list= fill + N_NODES;

    hipMemsetAsync(m_u, 0, (size_t)N_NODES * HEADS * sizeof(unsigned), stream);
    hipMemsetAsync(z,   0, (size_t)N_NODES * HEADS * sizeof(float), stream);
    hipMemsetAsync(deg, 0, (size_t)N_NODES * sizeof(int), stream);
    hipMemsetAsync(fill,0, (size_t)N_NODES * sizeof(int), stream);

    dim3 gemm_grid((N_NODES + 63) / 64, 4);
    gemm_bias<<<gemm_grid, 256, 0, stream>>>(x, Wq, bq, q);
    gemm_bias<<<gemm_grid, 256, 0, stream>>>(x, Wk, bk, k);
    gemm_bias<<<gemm_grid, 256, 0, stream>>>(x, Wv, bv, v);

    // CSR build overlaps conceptually with GEMMs but stream-serial is fine.
    deg_hist<<<(N_EDGES + 255) / 256, 256, 0, stream>>>(dst, deg);
    scan_deg<<<1, 256, 0, stream>>>(deg, rowptr);
    csr_scatter<<<(N_EDGES + 255) / 256, 256, 0, stream>>>(dst, rowptr, fill, edge_list);

    edge_scores<<<N_EDGES / 4, 256, 0, stream>>>(q, k, src, dst, scores, m_u);
    edge_exp<<<(N_EDGES * HEADS) / 256, 256, 0, stream>>>(dst, scores, m_u, z);
    node_aggregate<<<(N_NODES + 3) / 4, 256, 0, stream>>>(v, src, scores, z, rowptr, edge_list, out);
}

// Round 3
// 654.869 us; speedup vs baseline: 5.0974x; 1.4941x over previous
//
#include <hip/hip_runtime.h>
#include <math.h>

#define N_NODES 50000
#define N_EDGES 800000
#define DIM 256
#define HEADS 8
#define DIM_OUT 32
#define INNER 256        // HEADS*DIM_OUT
#define M_PAD 50048      // 391 * 128

typedef __attribute__((ext_vector_type(8))) short bf16x8;
typedef __attribute__((ext_vector_type(4))) float f32x4;

// round-to-nearest-even f32 -> bf16 bits
__device__ __forceinline__ unsigned short f2bf(float f) {
    unsigned u = __float_as_uint(f);
    unsigned r = (u + 0x7FFFu + ((u >> 16) & 1u)) >> 16;
    return (unsigned short)r;
}

// ---------------------------------------------------------------------------
// Convert x [50000,256] f32 -> bf16, zero-pad rows to M_PAD. 8 elems/thread.
// ---------------------------------------------------------------------------
__global__ __launch_bounds__(256) void conv_x(
    const float* __restrict__ x, unsigned short* __restrict__ xbf)
{
    size_t i8 = ((size_t)blockIdx.x * 256 + threadIdx.x) * 8;
    if (i8 >= (size_t)M_PAD * 256) return;
    unsigned short h[8];
    if (i8 < (size_t)N_NODES * 256) {
        float4 a = *(const float4*)(x + i8);
        float4 b = *(const float4*)(x + i8 + 4);
        h[0]=f2bf(a.x); h[1]=f2bf(a.y); h[2]=f2bf(a.z); h[3]=f2bf(a.w);
        h[4]=f2bf(b.x); h[5]=f2bf(b.y); h[6]=f2bf(b.z); h[7]=f2bf(b.w);
    } else {
        for (int j = 0; j < 8; j++) h[j] = 0;
    }
    uint4 o;
    o.x = (unsigned)h[0] | ((unsigned)h[1] << 16);
    o.y = (unsigned)h[2] | ((unsigned)h[3] << 16);
    o.z = (unsigned)h[4] | ((unsigned)h[5] << 16);
    o.w = (unsigned)h[6] | ((unsigned)h[7] << 16);
    *(uint4*)(xbf + i8) = o;
}

// ---------------------------------------------------------------------------
// Convert + transpose W[k][n] f32 -> Wt[n][k] bf16, for q/k/v (z = idx>>16).
// ---------------------------------------------------------------------------
__global__ __launch_bounds__(256) void conv_w(
    const float* __restrict__ Wq, const float* __restrict__ Wk,
    const float* __restrict__ Wv, unsigned short* __restrict__ Wt)
{
    int idx = blockIdx.x * 256 + threadIdx.x;   // < 3*65536
    int z = idx >> 16, r = idx & 65535;
    int k = r >> 8, n = r & 255;
    const float* W = (z == 0) ? Wq : (z == 1) ? Wk : Wv;
    Wt[(size_t)z * 65536 + n * 256 + k] = f2bf(W[k * 256 + n]);
}

// ---------------------------------------------------------------------------
// Fused QKV GEMM: C_z[M,256] = xbf @ W_z + b_z, bf16 MFMA 16x16x32.
// 128x128 tile, 256 threads = 4 waves, each wave 64x64 (4x4 MFMA frags).
// LDS rows stride 40 shorts (80 B = 5*16 B: b128-aligned, 2-way bank alias).
// ---------------------------------------------------------------------------
__global__ __launch_bounds__(256) void gemm_qkv(
    const unsigned short* __restrict__ xbf,
    const unsigned short* __restrict__ Wt,   // [3][n][k] bf16
    const float* __restrict__ bq, const float* __restrict__ bk,
    const float* __restrict__ bv,
    float* __restrict__ q, float* __restrict__ k, float* __restrict__ v)
{
    const int t = threadIdx.x;
    const int row0 = blockIdx.x * 128;
    const int col0 = blockIdx.y * 128;
    const int z = blockIdx.z;
    const unsigned short* Wz = Wt + (size_t)z * 65536;
    const float* bias = (z == 0) ? bq : (z == 1) ? bk : bv;
    float* C = (z == 0) ? q : (z == 1) ? k : v;

    __shared__ short As[128 * 40];
    __shared__ short Bs[128 * 40];

    const int wave = t >> 6;
    const int lane = t & 63;
    const int wm = (wave & 1) * 64;
    const int wn = (wave >> 1) * 64;
    const int lr = lane & 15;     // row/col within 16x16
    const int lg = lane >> 4;     // k-group (8 elems each)

    f32x4 acc[4][4] = {};

    for (int k0 = 0; k0 < 256; k0 += 32) {
        // stage A: 128 rows x 32 k = 512 chunks of 8 bf16; 2 per thread
        #pragma unroll
        for (int i = 0; i < 2; i++) {
            int idx = i * 256 + t;
            int row = idx >> 2, ch = idx & 3;
            uint4 val = *(const uint4*)(xbf + (size_t)(row0 + row) * 256 + k0 + ch * 8);
            *(uint4*)&As[row * 40 + ch * 8] = val;
        }
        // stage B (Wt is [n][k]): 128 n-rows x 32 k
        #pragma unroll
        for (int i = 0; i < 2; i++) {
            int idx = i * 256 + t;
            int n = idx >> 2, ch = idx & 3;
            uint4 val = *(const uint4*)(Wz + (size_t)(col0 + n) * 256 + k0 + ch * 8);
            *(uint4*)&Bs[n * 40 + ch * 8] = val;
        }
        __syncthreads();

        bf16x8 af[4], bf[4];
        #pragma unroll
        for (int mi = 0; mi < 4; mi++)
            af[mi] = *(const bf16x8*)&As[(wm + mi * 16 + lr) * 40 + lg * 8];
        #pragma unroll
        for (int ni = 0; ni < 4; ni++)
            bf[ni] = *(const bf16x8*)&Bs[(wn + ni * 16 + lr) * 40 + lg * 8];
        #pragma unroll
        for (int mi = 0; mi < 4; mi++)
            #pragma unroll
            for (int ni = 0; ni < 4; ni++)
                acc[mi][ni] = __builtin_amdgcn_mfma_f32_16x16x32_bf16(
                    af[mi], bf[ni], acc[mi][ni], 0, 0, 0);
        __syncthreads();
    }

    // epilogue: C/D layout col=lane&15, row=(lane>>4)*4+reg  [m89-verified]
    #pragma unroll
    for (int mi = 0; mi < 4; mi++) {
        #pragma unroll
        for (int ni = 0; ni < 4; ni++) {
            int gcol = col0 + wn + ni * 16 + lr;
            float bb = bias[gcol];
            #pragma unroll
            for (int r = 0; r < 4; r++) {
                int grow = row0 + wm + mi * 16 + lg * 4 + r;
                if (grow < N_NODES)
                    C[(size_t)grow * 256 + gcol] = acc[mi][ni][r] + bb;
            }
        }
    }
}

// ---------------------------------------------------------------------------
// CSR build: histogram -> single-block scan -> scatter
// ---------------------------------------------------------------------------
__global__ __launch_bounds__(256) void deg_hist(
    const int* __restrict__ dst, int* __restrict__ deg)
{
    int e = blockIdx.x * 256 + threadIdx.x;
    if (e < N_EDGES) atomicAdd(deg + dst[e], 1);
}

__global__ __launch_bounds__(256) void scan_deg(
    const int* __restrict__ deg, int* __restrict__ rowptr)
{
    const int CH = (N_NODES + 255) / 256;
    int t = threadIdx.x;
    int beg = t * CH;
    int end = min(beg + CH, N_NODES);
    int sum = 0;
    for (int i = beg; i < end; i++) sum += deg[i];

    __shared__ int s[256];
    s[t] = sum;
    __syncthreads();
    for (int off = 1; off < 256; off <<= 1) {
        int u = (t >= off) ? s[t - off] : 0;
        __syncthreads();
        s[t] += u;
        __syncthreads();
    }
    int run = s[t] - sum;
    for (int i = beg; i < end; i++) {
        run += deg[i];
        rowptr[i + 1] = run;
    }
    if (t == 0) rowptr[0] = 0;
}

__global__ __launch_bounds__(256) void csr_scatter(
    const int* __restrict__ dst, const int* __restrict__ rowptr,
    int* __restrict__ fill, int* __restrict__ edge_list)
{
    int e = blockIdx.x * 256 + threadIdx.x;
    if (e >= N_EDGES) return;
    int d = dst[e];
    int pos = rowptr[d] + atomicAdd(fill + d, 1);
    edge_list[pos] = e;
}

// ---------------------------------------------------------------------------
// Fused attention per dst node: one wave per node.
// k[d] held in registers; pass 1: gather q[src], dot, online softmax, store
// raw score; pass 2: re-read score, gather v[src], accumulate, single write.
// Lane l: head = l>>3, dims [4l,4l+4). No atomics anywhere.
// ---------------------------------------------------------------------------
__global__ __launch_bounds__(256) void node_attn(
    const float* __restrict__ q, const float* __restrict__ k,
    const float* __restrict__ v,
    const int* __restrict__ src,
    const int* __restrict__ rowptr, const int* __restrict__ edge_list,
    float* __restrict__ scores, float* __restrict__ out)
{
    int node = blockIdx.x * 4 + (threadIdx.x >> 6);
    int lane = threadIdx.x & 63;
    if (node >= N_NODES) return;
    int h = lane >> 3;
    float4 kv = *(const float4*)(k + (size_t)node * 256 + lane * 4);
    int beg = rowptr[node], end = rowptr[node + 1];

    float m = -INFINITY, zsum = 0.0f;
    for (int i = beg; i < end; i++) {
        int e = edge_list[i];
        int s = src[e];
        float4 qv = *(const float4*)(q + (size_t)s * 256 + lane * 4);
        float t = qv.x * kv.x + qv.y * kv.y + qv.z * kv.z + qv.w * kv.w;
        t += __shfl_xor(t, 1);
        t += __shfl_xor(t, 2);
        t += __shfl_xor(t, 4);   // all 8 lanes of the head group hold the dot
        float sc = t * 0.17677669529663687f;   // 1/sqrt(32)
        if ((lane & 7) == 0) scores[(size_t)e * 8 + h] = sc;
        float mn = fmaxf(m, sc);
        zsum = zsum * __expf(m - mn) + __expf(sc - mn);
        m = mn;
    }
    float inv = 1.0f / fmaxf(zsum, 1e-16f);

    float ax = 0.f, ay = 0.f, az = 0.f, aw = 0.f;
    for (int i = beg; i < end; i++) {
        int e = edge_list[i];
        int s = src[e];
        float p = __expf(scores[(size_t)e * 8 + h] - m) * inv;
        float4 vv = *(const float4*)(v + (size_t)s * 256 + lane * 4);
        ax += p * vv.x;
        ay += p * vv.y;
        az += p * vv.z;
        aw += p * vv.w;
    }
    float4 o = {ax, ay, az, aw};
    *(float4*)(out + (size_t)node * 256 + lane * 4) = o;
}

// ---------------------------------------------------------------------------
extern "C" void kernel_launch(void* const* d_in, const int* in_sizes, int n_in,
                              void* d_out, int out_size, void* d_ws, size_t ws_size,
                              hipStream_t stream) {
    const float* x  = (const float*)d_in[0];
    const float* Wq = (const float*)d_in[1];
    const float* bq = (const float*)d_in[2];
    const float* Wk = (const float*)d_in[3];
    const float* bk = (const float*)d_in[4];
    const float* Wv = (const float*)d_in[5];
    const float* bv = (const float*)d_in[6];
    const int* src  = (const int*)d_in[7];
    const int* dst  = (const int*)d_in[8];
    float* out = (float*)d_out;

    // workspace: q,k,v f32 [N,256] (51.2MB ea); xbf (bf16 [M_PAD,256], 25.6MB)
    // ALIASED with scores (f32 [E,8], 25.6MB — xbf dead after GEMMs);
    // Wt bf16 [3,256,256]; CSR ints. Total ~183 MB.
    float* q      = (float*)d_ws;
    float* k      = q + (size_t)N_NODES * INNER;
    float* v      = k + (size_t)N_NODES * INNER;
    char*  alias  = (char*)(v + (size_t)N_NODES * INNER);
    unsigned short* xbf = (unsigned short*)alias;           // 25,624,576 B
    float* scores = (float*)alias;                          // 25,600,000 B
    unsigned short* Wt = (unsigned short*)(alias + (size_t)M_PAD * 256 * 2);
    int* deg      = (int*)(Wt + 3 * 65536);
    int* rowptr   = deg + N_NODES;
    int* fill     = rowptr + (N_NODES + 1);
    int* edge_list= fill + N_NODES;

    hipMemsetAsync(deg,  0, (size_t)N_NODES * sizeof(int), stream);
    hipMemsetAsync(fill, 0, (size_t)N_NODES * sizeof(int), stream);

    // convert inputs to bf16
    conv_x<<<(M_PAD * 256 / 8 + 255) / 256, 256, 0, stream>>>(x, xbf);
    conv_w<<<3 * 65536 / 256, 256, 0, stream>>>(Wq, Wk, Wv, Wt);

    // fused QKV MFMA GEMM
    dim3 gg(M_PAD / 128, 2, 3);
    gemm_qkv<<<gg, 256, 0, stream>>>(xbf, Wt, bq, bk, bv, q, k, v);

    // CSR by dst
    deg_hist<<<(N_EDGES + 255) / 256, 256, 0, stream>>>(dst, deg);
    scan_deg<<<1, 256, 0, stream>>>(deg, rowptr);
    csr_scatter<<<(N_EDGES + 255) / 256, 256, 0, stream>>>(dst, rowptr, fill, edge_list);

    // fused scores + softmax + aggregate (scores buffer reuses xbf space)
    node_attn<<<(N_NODES + 3) / 4, 256, 0, stream>>>(
        q, k, v, src, rowptr, edge_list, scores, out);
}

// Round 4
// 461.170 us; speedup vs baseline: 7.2385x; 1.4200x over previous
//
#include <hip/hip_runtime.h>
#include <math.h>

#define N_NODES 50000
#define N_EDGES 800000
#define DIM 256
#define HEADS 8
#define DIM_OUT 32
#define INNER 256        // HEADS*DIM_OUT
#define M_PAD 50048      // 391 * 128

typedef __attribute__((ext_vector_type(8))) short bf16x8;
typedef __attribute__((ext_vector_type(4))) float f32x4;

// round-to-nearest-even f32 -> bf16 bits
__device__ __forceinline__ unsigned short f2bf(float f) {
    unsigned u = __float_as_uint(f);
    unsigned r = (u + 0x7FFFu + ((u >> 16) & 1u)) >> 16;
    return (unsigned short)r;
}

__device__ __forceinline__ void unpack_bf8(uint4 r, float* f) {
    f[0] = __uint_as_float(r.x << 16);
    f[1] = __uint_as_float(r.x & 0xFFFF0000u);
    f[2] = __uint_as_float(r.y << 16);
    f[3] = __uint_as_float(r.y & 0xFFFF0000u);
    f[4] = __uint_as_float(r.z << 16);
    f[5] = __uint_as_float(r.z & 0xFFFF0000u);
    f[6] = __uint_as_float(r.w << 16);
    f[7] = __uint_as_float(r.w & 0xFFFF0000u);
}

// ---------------------------------------------------------------------------
// Convert x [50000,256] f32 -> bf16, zero-pad rows to M_PAD.
// ---------------------------------------------------------------------------
__global__ __launch_bounds__(256) void conv_x(
    const float* __restrict__ x, unsigned short* __restrict__ xbf)
{
    size_t i8 = ((size_t)blockIdx.x * 256 + threadIdx.x) * 8;
    if (i8 >= (size_t)M_PAD * 256) return;
    unsigned short h[8];
    if (i8 < (size_t)N_NODES * 256) {
        float4 a = *(const float4*)(x + i8);
        float4 b = *(const float4*)(x + i8 + 4);
        h[0]=f2bf(a.x); h[1]=f2bf(a.y); h[2]=f2bf(a.z); h[3]=f2bf(a.w);
        h[4]=f2bf(b.x); h[5]=f2bf(b.y); h[6]=f2bf(b.z); h[7]=f2bf(b.w);
    } else {
        for (int j = 0; j < 8; j++) h[j] = 0;
    }
    uint4 o;
    o.x = (unsigned)h[0] | ((unsigned)h[1] << 16);
    o.y = (unsigned)h[2] | ((unsigned)h[3] << 16);
    o.z = (unsigned)h[4] | ((unsigned)h[5] << 16);
    o.w = (unsigned)h[6] | ((unsigned)h[7] << 16);
    *(uint4*)(xbf + i8) = o;
}

// ---------------------------------------------------------------------------
// Convert + transpose W[k][n] f32 -> Wt[n][k] bf16, for q/k/v (z = idx>>16).
// ---------------------------------------------------------------------------
__global__ __launch_bounds__(256) void conv_w(
    const float* __restrict__ Wq, const float* __restrict__ Wk,
    const float* __restrict__ Wv, unsigned short* __restrict__ Wt)
{
    int idx = blockIdx.x * 256 + threadIdx.x;   // < 3*65536
    int z = idx >> 16, r = idx & 65535;
    int k = r >> 8, n = r & 255;
    const float* W = (z == 0) ? Wq : (z == 1) ? Wk : Wv;
    Wt[(size_t)z * 65536 + n * 256 + k] = f2bf(W[k * 256 + n]);
}

// ---------------------------------------------------------------------------
// Fused QKV GEMM: bf16 MFMA 16x16x32, 128x128 tile, OUTPUT bf16 (q/k/v).
// ---------------------------------------------------------------------------
__global__ __launch_bounds__(256) void gemm_qkv(
    const unsigned short* __restrict__ xbf,
    const unsigned short* __restrict__ Wt,   // [3][n][k] bf16
    const float* __restrict__ bq, const float* __restrict__ bk,
    const float* __restrict__ bv,
    unsigned short* __restrict__ q, unsigned short* __restrict__ k,
    unsigned short* __restrict__ v)
{
    const int t = threadIdx.x;
    const int row0 = blockIdx.x * 128;
    const int col0 = blockIdx.y * 128;
    const int z = blockIdx.z;
    const unsigned short* Wz = Wt + (size_t)z * 65536;
    const float* bias = (z == 0) ? bq : (z == 1) ? bk : bv;
    unsigned short* C = (z == 0) ? q : (z == 1) ? k : v;

    __shared__ short As[128 * 40];
    __shared__ short Bs[128 * 40];

    const int wave = t >> 6;
    const int lane = t & 63;
    const int wm = (wave & 1) * 64;
    const int wn = (wave >> 1) * 64;
    const int lr = lane & 15;
    const int lg = lane >> 4;

    f32x4 acc[4][4] = {};

    for (int k0 = 0; k0 < 256; k0 += 32) {
        #pragma unroll
        for (int i = 0; i < 2; i++) {
            int idx = i * 256 + t;
            int row = idx >> 2, ch = idx & 3;
            uint4 val = *(const uint4*)(xbf + (size_t)(row0 + row) * 256 + k0 + ch * 8);
            *(uint4*)&As[row * 40 + ch * 8] = val;
        }
        #pragma unroll
        for (int i = 0; i < 2; i++) {
            int idx = i * 256 + t;
            int n = idx >> 2, ch = idx & 3;
            uint4 val = *(const uint4*)(Wz + (size_t)(col0 + n) * 256 + k0 + ch * 8);
            *(uint4*)&Bs[n * 40 + ch * 8] = val;
        }
        __syncthreads();

        bf16x8 af[4], bfr[4];
        #pragma unroll
        for (int mi = 0; mi < 4; mi++)
            af[mi] = *(const bf16x8*)&As[(wm + mi * 16 + lr) * 40 + lg * 8];
        #pragma unroll
        for (int ni = 0; ni < 4; ni++)
            bfr[ni] = *(const bf16x8*)&Bs[(wn + ni * 16 + lr) * 40 + lg * 8];
        #pragma unroll
        for (int mi = 0; mi < 4; mi++)
            #pragma unroll
            for (int ni = 0; ni < 4; ni++)
                acc[mi][ni] = __builtin_amdgcn_mfma_f32_16x16x32_bf16(
                    af[mi], bfr[ni], acc[mi][ni], 0, 0, 0);
        __syncthreads();
    }

    // epilogue: C/D layout col=lane&15, row=(lane>>4)*4+reg  [m89-verified]
    #pragma unroll
    for (int mi = 0; mi < 4; mi++) {
        #pragma unroll
        for (int ni = 0; ni < 4; ni++) {
            int gcol = col0 + wn + ni * 16 + lr;
            float bb = bias[gcol];
            #pragma unroll
            for (int r = 0; r < 4; r++) {
                int grow = row0 + wm + mi * 16 + lg * 4 + r;
                if (grow < N_NODES)
                    C[(size_t)grow * 256 + gcol] = f2bf(acc[mi][ni][r] + bb);
            }
        }
    }
}

// ---------------------------------------------------------------------------
// CSR build: histogram -> single-block scan -> scatter
// ---------------------------------------------------------------------------
__global__ __launch_bounds__(256) void deg_hist(
    const int* __restrict__ dst, int* __restrict__ deg)
{
    int e = blockIdx.x * 256 + threadIdx.x;
    if (e < N_EDGES) atomicAdd(deg + dst[e], 1);
}

__global__ __launch_bounds__(1024) void scan_deg(
    const int* __restrict__ deg, int* __restrict__ rowptr)
{
    const int CH = (N_NODES + 1023) / 1024;  // 49
    int t = threadIdx.x;
    int beg = t * CH;
    int end = min(beg + CH, N_NODES);
    int sum = 0;
    for (int i = beg; i < end; i++) sum += deg[i];

    __shared__ int s[1024];
    s[t] = sum;
    __syncthreads();
    for (int off = 1; off < 1024; off <<= 1) {
        int u = (t >= off) ? s[t - off] : 0;
        __syncthreads();
        s[t] += u;
        __syncthreads();
    }
    int run = s[t] - sum;
    for (int i = beg; i < end; i++) {
        run += deg[i];
        rowptr[i + 1] = run;
    }
    if (t == 0) rowptr[0] = 0;
}

__global__ __launch_bounds__(256) void csr_scatter(
    const int* __restrict__ dst, const int* __restrict__ rowptr,
    int* __restrict__ fill, int* __restrict__ edge_list)
{
    int e = blockIdx.x * 256 + threadIdx.x;
    if (e >= N_EDGES) return;
    int d = dst[e];
    int pos = rowptr[d] + atomicAdd(fill + d, 1);
    edge_list[pos] = e;
}

// ---------------------------------------------------------------------------
// Fused single-pass attention per dst node. One wave per node, HALF-WAVE per
// edge (32 lanes x 8 bf16 = 256 dims). Flash-style online softmax rescaling
// of the output accumulator — no scores array, no second pass, no atomics.
// Lane l in [0,32): dims [8l,8l+8), head h = l>>2 (4 lanes per head).
// src prefetched 2 iters ahead; q/v row loads issue 1 full body before use.
// ---------------------------------------------------------------------------
__global__ __launch_bounds__(256) void node_attn(
    const unsigned short* __restrict__ qbf,
    const unsigned short* __restrict__ kbf,
    const unsigned short* __restrict__ vbf,
    const int* __restrict__ src,
    const int* __restrict__ rowptr, const int* __restrict__ edge_list,
    float* __restrict__ out)
{
    int node = blockIdx.x * 4 + (threadIdx.x >> 6);
    int lane = threadIdx.x & 63;
    if (node >= N_NODES) return;
    const int half = lane >> 5;
    const int l = lane & 31;

    uint4 kraw = *(const uint4*)(kbf + (size_t)node * 256 + l * 8);
    float kf[8];
    unpack_bf8(kraw, kf);

    int beg = rowptr[node], end = rowptr[node + 1];

    float m = -INFINITY, zsum = 0.0f;
    float af[8] = {};

    // pipeline: s0 = current (rows loaded), s1 = next (src loaded), fetch s2
    int i0 = beg + half;
    bool val0 = i0 < end;
    bool val1 = (i0 + 2) < end;
    int s0 = 0, s1 = 0;
    if (val0) s0 = src[edge_list[i0]];
    if (val1) s1 = src[edge_list[i0 + 2]];
    uint4 q0 = {}, v0 = {};
    if (val0) {
        q0 = *(const uint4*)(qbf + (size_t)s0 * 256 + l * 8);
        v0 = *(const uint4*)(vbf + (size_t)s0 * 256 + l * 8);
    }
    int ii = i0 + 4;

    while (val0) {
        // issue next row loads (s1 known since previous iteration)
        uint4 q1 = {}, v1 = {};
        if (val1) {
            q1 = *(const uint4*)(qbf + (size_t)s1 * 256 + l * 8);
            v1 = *(const uint4*)(vbf + (size_t)s1 * 256 + l * 8);
        }
        // prefetch s2
        bool val2 = ii < end;
        int s2 = 0;
        if (val2) s2 = src[edge_list[ii]];
        ii += 2;

        // compute with current rows
        float qf[8], vf[8];
        unpack_bf8(q0, qf);
        unpack_bf8(v0, vf);
        float t = qf[0]*kf[0] + qf[1]*kf[1] + qf[2]*kf[2] + qf[3]*kf[3]
                + qf[4]*kf[4] + qf[5]*kf[5] + qf[6]*kf[6] + qf[7]*kf[7];
        t += __shfl_xor(t, 1);
        t += __shfl_xor(t, 2);   // all 4 lanes of the head group hold the dot
        float sc = t * 0.17677669529663687f;   // 1/sqrt(32)
        float mn = fmaxf(m, sc);
        float alpha = __expf(m - mn);   // first iter: exp(-inf)=0, mn finite
        float w = __expf(sc - mn);
        zsum = zsum * alpha + w;
        #pragma unroll
        for (int j = 0; j < 8; j++) af[j] = af[j] * alpha + w * vf[j];
        m = mn;

        // shift pipeline
        q0 = q1; v0 = v1; s0 = s1; s1 = s2;
        val0 = val1; val1 = val2;
    }

    // combine halves: rescale to common max, sum across lane^32
    float mo = __shfl_xor(m, 32);
    float mt = fmaxf(m, mo);
    float scale = (m == -INFINITY) ? 0.0f : __expf(m - mt);
    zsum *= scale;
    #pragma unroll
    for (int j = 0; j < 8; j++) af[j] *= scale;
    zsum += __shfl_xor(zsum, 32);
    #pragma unroll
    for (int j = 0; j < 8; j++) af[j] += __shfl_xor(af[j], 32);

    float inv = 1.0f / fmaxf(zsum, 1e-16f);
    if (half == 0) {
        float4 o0 = {af[0]*inv, af[1]*inv, af[2]*inv, af[3]*inv};
        float4 o1 = {af[4]*inv, af[5]*inv, af[6]*inv, af[7]*inv};
        float* op = out + (size_t)node * 256 + l * 8;
        *(float4*)op = o0;
        *(float4*)(op + 4) = o1;
    }
}

// ---------------------------------------------------------------------------
extern "C" void kernel_launch(void* const* d_in, const int* in_sizes, int n_in,
                              void* d_out, int out_size, void* d_ws, size_t ws_size,
                              hipStream_t stream) {
    const float* x  = (const float*)d_in[0];
    const float* Wq = (const float*)d_in[1];
    const float* bq = (const float*)d_in[2];
    const float* Wk = (const float*)d_in[3];
    const float* bk = (const float*)d_in[4];
    const float* Wv = (const float*)d_in[5];
    const float* bv = (const float*)d_in[6];
    const int* src  = (const int*)d_in[7];
    const int* dst  = (const int*)d_in[8];
    float* out = (float*)d_out;

    // workspace: qbf/kbf/vbf bf16 [N,256] (25.6MB ea); xbf bf16 [M_PAD,256];
    // Wt bf16 [3,256,256]; CSR ints. ~106 MB total.
    unsigned short* qbf = (unsigned short*)d_ws;
    unsigned short* kbf = qbf + (size_t)N_NODES * INNER;
    unsigned short* vbf = kbf + (size_t)N_NODES * INNER;
    unsigned short* xbf = vbf + (size_t)N_NODES * INNER;
    unsigned short* Wt  = xbf + (size_t)M_PAD * INNER;
    int* deg      = (int*)(Wt + 3 * 65536);
    int* rowptr   = deg + N_NODES;
    int* fill     = rowptr + (N_NODES + 1);
    int* edge_list= fill + N_NODES;

    hipMemsetAsync(deg,  0, (size_t)N_NODES * sizeof(int), stream);
    hipMemsetAsync(fill, 0, (size_t)N_NODES * sizeof(int), stream);

    conv_x<<<(M_PAD * 256 / 8 + 255) / 256, 256, 0, stream>>>(x, xbf);
    conv_w<<<3 * 65536 / 256, 256, 0, stream>>>(Wq, Wk, Wv, Wt);

    dim3 gg(M_PAD / 128, 2, 3);
    gemm_qkv<<<gg, 256, 0, stream>>>(xbf, Wt, bq, bk, bv, qbf, kbf, vbf);

    deg_hist<<<(N_EDGES + 255) / 256, 256, 0, stream>>>(dst, deg);
    scan_deg<<<1, 1024, 0, stream>>>(deg, rowptr);
    csr_scatter<<<(N_EDGES + 255) / 256, 256, 0, stream>>>(dst, rowptr, fill, edge_list);

    node_attn<<<(N_NODES + 3) / 4, 256, 0, stream>>>(
        qbf, kbf, vbf, src, rowptr, edge_list, out);
}

// Round 5
// 390.110 us; speedup vs baseline: 8.5570x; 1.1822x over previous
//
#include <hip/hip_runtime.h>
#include <math.h>

#define N_NODES 50000
#define N_EDGES 800000
#define DIM 256
#define HEADS 8
#define DIM_OUT 32
#define INNER 256        // HEADS*DIM_OUT
#define M_PAD 50048      // 391 * 128

typedef __attribute__((ext_vector_type(8))) short bf16x8;
typedef __attribute__((ext_vector_type(4))) float f32x4;
typedef __attribute__((ext_vector_type(2))) float f32x2;

// round-to-nearest-even f32 -> bf16 bits
__device__ __forceinline__ unsigned short f2bf(float f) {
    unsigned u = __float_as_uint(f);
    unsigned r = (u + 0x7FFFu + ((u >> 16) & 1u)) >> 16;
    return (unsigned short)r;
}

// unpack uint (2 packed bf16) -> f32x2
__device__ __forceinline__ f32x2 up2(unsigned u) {
    f32x2 r;
    r.x = __uint_as_float(u << 16);
    r.y = __uint_as_float(u & 0xFFFF0000u);
    return r;
}
__device__ __forceinline__ void up2x4(uint4 r, f32x2* o) {
    o[0] = up2(r.x); o[1] = up2(r.y); o[2] = up2(r.z); o[3] = up2(r.w);
}

// global -> LDS direct copy, 16 B per lane, dest = wave-uniform base + lane*16
__device__ __forceinline__ void gll16(const void* g, void* l) {
    __builtin_amdgcn_global_load_lds(
        (const __attribute__((address_space(1))) unsigned*)(uintptr_t)g,
        (__attribute__((address_space(3))) unsigned*)(unsigned)(uintptr_t)l,
        16, 0, 0);
}

// ---------------------------------------------------------------------------
// prep: conv_x (6256 blocks) + conv_w (768) + deg_hist (3125), one dispatch.
// ---------------------------------------------------------------------------
#define NB_CONVX 6256   // M_PAD*256/8/256
#define NB_CONVW 768    // 3*65536/256
#define NB_HIST  3125   // N_EDGES/256
__global__ __launch_bounds__(256) void prep(
    const float* __restrict__ x,
    const float* __restrict__ Wq, const float* __restrict__ Wk,
    const float* __restrict__ Wv,
    const int* __restrict__ dst,
    unsigned short* __restrict__ xbf, unsigned short* __restrict__ Wt,
    int* __restrict__ deg)
{
    int b = blockIdx.x;
    if (b < NB_CONVX) {
        size_t i8 = ((size_t)b * 256 + threadIdx.x) * 8;
        unsigned short h[8];
        if (i8 < (size_t)N_NODES * 256) {
            float4 a = *(const float4*)(x + i8);
            float4 c = *(const float4*)(x + i8 + 4);
            h[0]=f2bf(a.x); h[1]=f2bf(a.y); h[2]=f2bf(a.z); h[3]=f2bf(a.w);
            h[4]=f2bf(c.x); h[5]=f2bf(c.y); h[6]=f2bf(c.z); h[7]=f2bf(c.w);
        } else {
            #pragma unroll
            for (int j = 0; j < 8; j++) h[j] = 0;
        }
        uint4 o;
        o.x = (unsigned)h[0] | ((unsigned)h[1] << 16);
        o.y = (unsigned)h[2] | ((unsigned)h[3] << 16);
        o.z = (unsigned)h[4] | ((unsigned)h[5] << 16);
        o.w = (unsigned)h[6] | ((unsigned)h[7] << 16);
        *(uint4*)(xbf + i8) = o;
    } else if (b < NB_CONVX + NB_CONVW) {
        int idx = (b - NB_CONVX) * 256 + threadIdx.x;   // < 3*65536
        int z = idx >> 16, r = idx & 65535;
        int k = r >> 8, n = r & 255;
        const float* W = (z == 0) ? Wq : (z == 1) ? Wk : Wv;
        Wt[(size_t)z * 65536 + n * 256 + k] = f2bf(W[k * 256 + n]);
    } else {
        int e = (b - NB_CONVX - NB_CONVW) * 256 + threadIdx.x;
        if (e < N_EDGES) atomicAdd(deg + dst[e], 1);
    }
}

// ---------------------------------------------------------------------------
// Fused QKV GEMM: bf16 MFMA 16x16x32, 128x128 tile, m97-style staging via
// global_load_lds (width 16). LDS rows stride 32 shorts (64 B), unpadded
// (global_load_lds dest is wave-uniform base + lane*16 — no padding allowed).
// ---------------------------------------------------------------------------
__global__ __launch_bounds__(256) void gemm_qkv(
    const unsigned short* __restrict__ xbf,
    const unsigned short* __restrict__ Wt,   // [3][n][k] bf16
    const float* __restrict__ bq, const float* __restrict__ bk,
    const float* __restrict__ bv,
    unsigned short* __restrict__ q, unsigned short* __restrict__ k,
    unsigned short* __restrict__ v)
{
    const int t = threadIdx.x;
    const int row0 = blockIdx.x * 128;
    const int col0 = blockIdx.y * 128;
    const int z = blockIdx.z;
    const unsigned short* Wz = Wt + (size_t)z * 65536;
    const float* bias = (z == 0) ? bq : (z == 1) ? bk : bv;
    unsigned short* C = (z == 0) ? q : (z == 1) ? k : v;

    __shared__ __align__(16) short As[128 * 32];
    __shared__ __align__(16) short Bs[128 * 32];

    const int wave = t >> 6;
    const int lane = t & 63;
    const int wm = (wave & 1) * 64;
    const int wn = (wave >> 1) * 64;
    const int lr = lane & 15;
    const int lg = lane >> 4;
    const int srow = lane >> 2;       // staging: row within 16-row segment
    const int sch  = lane & 3;        // staging: 16-B chunk within row

    f32x4 acc[4][4] = {};

    for (int k0 = 0; k0 < 256; k0 += 32) {
        // A: 128 rows x 32 k; 8 segments of 16 rows; wave w does segs 2w,2w+1
        #pragma unroll
        for (int c = 0; c < 2; c++) {
            int seg = wave * 2 + c;
            gll16(xbf + (size_t)(row0 + seg * 16 + srow) * 256 + k0 + sch * 8,
                  As + seg * 512);      // 512 shorts = 16 rows * 32
        }
        #pragma unroll
        for (int c = 0; c < 2; c++) {
            int seg = wave * 2 + c;
            gll16(Wz + (size_t)(col0 + seg * 16 + srow) * 256 + k0 + sch * 8,
                  Bs + seg * 512);
        }
        __syncthreads();   // compiler emits vmcnt(0) drain before s_barrier

        bf16x8 af[4], bfr[4];
        #pragma unroll
        for (int mi = 0; mi < 4; mi++)
            af[mi] = *(const bf16x8*)&As[(wm + mi * 16 + lr) * 32 + lg * 8];
        #pragma unroll
        for (int ni = 0; ni < 4; ni++)
            bfr[ni] = *(const bf16x8*)&Bs[(wn + ni * 16 + lr) * 32 + lg * 8];
        #pragma unroll
        for (int mi = 0; mi < 4; mi++)
            #pragma unroll
            for (int ni = 0; ni < 4; ni++)
                acc[mi][ni] = __builtin_amdgcn_mfma_f32_16x16x32_bf16(
                    af[mi], bfr[ni], acc[mi][ni], 0, 0, 0);
        __syncthreads();
    }

    // epilogue: C/D layout col=lane&15, row=(lane>>4)*4+reg  [m89-verified]
    #pragma unroll
    for (int mi = 0; mi < 4; mi++) {
        #pragma unroll
        for (int ni = 0; ni < 4; ni++) {
            int gcol = col0 + wn + ni * 16 + lr;
            float bb = bias[gcol];
            #pragma unroll
            for (int r = 0; r < 4; r++) {
                int grow = row0 + wm + mi * 16 + lg * 4 + r;
                if (grow < N_NODES)
                    C[(size_t)grow * 256 + gcol] = f2bf(acc[mi][ni][r] + bb);
            }
        }
    }
}

// ---------------------------------------------------------------------------
// Coalesced single-block scan: int4 tiles of 4096, Hillis block-scan.
// ---------------------------------------------------------------------------
__global__ __launch_bounds__(1024) void scan_deg(
    const int* __restrict__ deg, int* __restrict__ rowptr)
{
    __shared__ int s[1024];
    int t = threadIdx.x;
    int carry = 0;
    for (int base = 0; base < N_NODES; base += 4096) {
        int i4 = base + t * 4;
        int4 dv = {0, 0, 0, 0};
        if (i4 < N_NODES) dv = *(const int4*)(deg + i4);  // N_NODES%4==0
        int sum = dv.x + dv.y + dv.z + dv.w;
        s[t] = sum;
        __syncthreads();
        for (int off = 1; off < 1024; off <<= 1) {
            int u = (t >= off) ? s[t - off] : 0;
            __syncthreads();
            s[t] += u;
            __syncthreads();
        }
        if (i4 < N_NODES) {
            int r = carry + s[t] - sum;
            r += dv.x; rowptr[i4 + 1] = r;
            r += dv.y; rowptr[i4 + 2] = r;
            r += dv.z; rowptr[i4 + 3] = r;
            r += dv.w; rowptr[i4 + 4] = r;
        }
        carry += s[1023];
        __syncthreads();
    }
    if (t == 0) rowptr[0] = 0;
}

// csr_scatter consumes deg via atomicSub (deg dead after scan) — no fill array
__global__ __launch_bounds__(256) void csr_scatter(
    const int* __restrict__ dst, const int* __restrict__ rowptr,
    int* __restrict__ deg, int* __restrict__ edge_list)
{
    int e = blockIdx.x * 256 + threadIdx.x;
    if (e >= N_EDGES) return;
    int d = dst[e];
    int old = atomicSub(deg + d, 1);      // old in [1..degree]
    edge_list[rowptr[d] + old - 1] = e;
}

// ---------------------------------------------------------------------------
// Fused single-pass attention per dst node. One wave per node, half-wave per
// edge stream (32 lanes x 8 bf16 = 256 dims). Flash-style online softmax.
// Prefetch depth 2: src indices 3 ahead, q/v rows 2 ahead. Packed f32x2 math.
// Lane l in [0,32): dims [8l,8l+8), head h = l>>2.
// ---------------------------------------------------------------------------
__global__ __launch_bounds__(256) void node_attn(
    const unsigned short* __restrict__ qbf,
    const unsigned short* __restrict__ kbf,
    const unsigned short* __restrict__ vbf,
    const int* __restrict__ src,
    const int* __restrict__ rowptr, const int* __restrict__ edge_list,
    float* __restrict__ out)
{
    int node = blockIdx.x * 4 + (threadIdx.x >> 6);
    int lane = threadIdx.x & 63;
    if (node >= N_NODES) return;
    const int half = lane >> 5;
    const int l = lane & 31;

    f32x2 kf2[4];
    up2x4(*(const uint4*)(kbf + (size_t)node * 256 + l * 8), kf2);

    int beg = rowptr[node], end = rowptr[node + 1];

    float m = -INFINITY, zsum = 0.0f;
    f32x2 af2[4] = {};

    int i0 = beg + half;                 // this half's stream, step 2
    bool va0 = i0 < end;
    bool va1 = (i0 + 2) < end;
    bool va2 = (i0 + 4) < end;
    int s0 = 0, s1 = 0, s2 = 0;
    if (va0) s0 = src[edge_list[i0]];
    if (va1) s1 = src[edge_list[i0 + 2]];
    if (va2) s2 = src[edge_list[i0 + 4]];
    uint4 q0 = {}, v0 = {}, q1 = {}, v1 = {};
    if (va0) {
        q0 = *(const uint4*)(qbf + (size_t)s0 * 256 + l * 8);
        v0 = *(const uint4*)(vbf + (size_t)s0 * 256 + l * 8);
    }
    if (va1) {
        q1 = *(const uint4*)(qbf + (size_t)s1 * 256 + l * 8);
        v1 = *(const uint4*)(vbf + (size_t)s1 * 256 + l * 8);
    }
    int ii = i0 + 6;

    while (va0) {
        // issue loads for edge i+2 (s2 known since previous iteration)
        uint4 q2 = {}, v2 = {};
        if (va2) {
            q2 = *(const uint4*)(qbf + (size_t)s2 * 256 + l * 8);
            v2 = *(const uint4*)(vbf + (size_t)s2 * 256 + l * 8);
        }
        // prefetch src for edge i+3
        bool va3 = ii < end;
        int s3 = 0;
        if (va3) s3 = src[edge_list[ii]];
        ii += 2;

        // compute with current rows (packed f32x2 -> v_pk_fma_f32)
        f32x2 qf2[4], vf2[4];
        up2x4(q0, qf2);
        up2x4(v0, vf2);
        f32x2 d2 = qf2[0] * kf2[0];
        d2 += qf2[1] * kf2[1];
        d2 += qf2[2] * kf2[2];
        d2 += qf2[3] * kf2[3];
        float t = d2.x + d2.y;
        t += __shfl_xor(t, 1);
        t += __shfl_xor(t, 2);   // 4 lanes of the head group hold the dot
        float sc = t * 0.17677669529663687f;   // 1/sqrt(32)
        float mn = fmaxf(m, sc);
        float alpha = __expf(m - mn);
        float w = __expf(sc - mn);
        zsum = zsum * alpha + w;
        f32x2 a2 = {alpha, alpha};
        f32x2 w2 = {w, w};
        #pragma unroll
        for (int j = 0; j < 4; j++) af2[j] = af2[j] * a2 + vf2[j] * w2;
        m = mn;

        // shift pipeline
        q0 = q1; v0 = v1; q1 = q2; v1 = v2;
        s2 = s3;
        va0 = va1; va1 = va2; va2 = va3;
    }

    // combine halves: rescale to common max, sum across lane^32
    float mo = __shfl_xor(m, 32);
    float mt = fmaxf(m, mo);
    float scale = (m == -INFINITY) ? 0.0f : __expf(m - mt);
    zsum *= scale;
    zsum += __shfl_xor(zsum, 32);
    #pragma unroll
    for (int j = 0; j < 4; j++) {
        af2[j].x = af2[j].x * scale;
        af2[j].y = af2[j].y * scale;
        af2[j].x += __shfl_xor(af2[j].x, 32);
        af2[j].y += __shfl_xor(af2[j].y, 32);
    }

    float inv = 1.0f / fmaxf(zsum, 1e-16f);
    if (half == 0) {
        float4 o0 = {af2[0].x * inv, af2[0].y * inv, af2[1].x * inv, af2[1].y * inv};
        float4 o1 = {af2[2].x * inv, af2[2].y * inv, af2[3].x * inv, af2[3].y * inv};
        float* op = out + (size_t)node * 256 + l * 8;
        *(float4*)op = o0;
        *(float4*)(op + 4) = o1;
    }
}

// ---------------------------------------------------------------------------
extern "C" void kernel_launch(void* const* d_in, const int* in_sizes, int n_in,
                              void* d_out, int out_size, void* d_ws, size_t ws_size,
                              hipStream_t stream) {
    const float* x  = (const float*)d_in[0];
    const float* Wq = (const float*)d_in[1];
    const float* bq = (const float*)d_in[2];
    const float* Wk = (const float*)d_in[3];
    const float* bk = (const float*)d_in[4];
    const float* Wv = (const float*)d_in[5];
    const float* bv = (const float*)d_in[6];
    const int* src  = (const int*)d_in[7];
    const int* dst  = (const int*)d_in[8];
    float* out = (float*)d_out;

    unsigned short* qbf = (unsigned short*)d_ws;
    unsigned short* kbf = qbf + (size_t)N_NODES * INNER;
    unsigned short* vbf = kbf + (size_t)N_NODES * INNER;
    unsigned short* xbf = vbf + (size_t)N_NODES * INNER;
    unsigned short* Wt  = xbf + (size_t)M_PAD * INNER;
    int* deg      = (int*)(Wt + 3 * 65536);
    int* rowptr   = deg + N_NODES;
    int* edge_list= rowptr + (N_NODES + 1);

    hipMemsetAsync(deg, 0, (size_t)N_NODES * sizeof(int), stream);

    prep<<<NB_CONVX + NB_CONVW + NB_HIST, 256, 0, stream>>>(
        x, Wq, Wk, Wv, dst, xbf, Wt, deg);

    dim3 gg(M_PAD / 128, 2, 3);
    gemm_qkv<<<gg, 256, 0, stream>>>(xbf, Wt, bq, bk, bv, qbf, kbf, vbf);

    scan_deg<<<1, 1024, 0, stream>>>(deg, rowptr);
    csr_scatter<<<(N_EDGES + 255) / 256, 256, 0, stream>>>(dst, rowptr, deg, edge_list);

    node_attn<<<(N_NODES + 3) / 4, 256, 0, stream>>>(
        qbf, kbf, vbf, src, rowptr, edge_list, out);
}